// Round 19
// baseline (490.792 us; speedup 1.0000x reference)
//
#include <hip/hip_runtime.h>
#include <hip/hip_bf16.h>

#define T_STEPS 8
#define F_IN    128
#define H_GCN   32
#define H_CONV  64
#define H_LSTM  128

typedef __bf16 bf16x8 __attribute__((ext_vector_type(8)));
typedef float  f32x4  __attribute__((ext_vector_type(4)));
typedef unsigned short ushort8v __attribute__((ext_vector_type(8)));

#if __has_builtin(__builtin_amdgcn_exp2f)
__device__ __forceinline__ float exp2_f(float x) { return __builtin_amdgcn_exp2f(x); }
#else
__device__ __forceinline__ float exp2_f(float x) { return exp2f(x); }
#endif
#if __has_builtin(__builtin_amdgcn_rcpf)
__device__ __forceinline__ float rcp_f(float x) { return __builtin_amdgcn_rcpf(x); }
#else
__device__ __forceinline__ float rcp_f(float x) { return 1.f / x; }
#endif

#define NL2E  (-1.442695041f)   // -log2(e)
#define NL2E2 (-2.885390082f)   // -2*log2(e)

__device__ __forceinline__ float sigm_fast(float x) {
  return rcp_f(1.f + exp2_f(x * NL2E));
}

__device__ __forceinline__ float ubf(unsigned short u) {
  union { unsigned int i; float f; } v; v.i = ((unsigned int)u) << 16; return v.f;
}
__device__ __forceinline__ unsigned short bfb(float f) {
  __hip_bfloat16 b = __float2bfloat16(f);
  return __builtin_bit_cast(unsigned short, b);
}

__device__ __forceinline__ bf16x8 load_bf8(const __hip_bfloat16* p) {
  int4 v = *reinterpret_cast<const int4*>(p);
  return __builtin_bit_cast(bf16x8, v);
}

#define PREP_TOT (512*192 + 64*128 + 128*64 + 64*64 + 32*128 + 512)

// ---------------- K1: MFMA transform + adjacency fill (fused; both depend only on scan) ----------------
__global__ __launch_bounds__(256) void k_transform_fill(
    const float* __restrict__ x,
    const __hip_bfloat16* __restrict__ Wgt, // [32][128]
    const float* __restrict__ dinv,
    __hip_bfloat16* __restrict__ hs,
    const int* __restrict__ ei, int* __restrict__ cursor,
    int* __restrict__ adj, int E)
{
  int tid  = threadIdx.x;

  // fill: 640K threads >= E; atomic latency overlaps MFMA below
  {
    int e = blockIdx.x * 256 + tid;
    if (e < E) {
      int r = ei[e], ctg = ei[E + e];
      int pos = atomicAdd(&cursor[ctg], 1);
      adj[pos] = r;
    }
  }

  int wave = tid >> 6;
  int lane = tid & 63;
  int l15  = lane & 15;
  int lhi  = lane >> 4;
  long r0  = (long)blockIdx.x * 64 + wave * 16;

  bf16x8 bw[2][4];
  #pragma unroll
  for (int ct = 0; ct < 2; ++ct)
    #pragma unroll
    for (int ks = 0; ks < 4; ++ks)
      bw[ct][ks] = load_bf8(Wgt + (ct * 16 + l15) * 128 + ks * 32 + lhi * 8);

  const float* xp = x + (r0 + l15) * 128 + lhi * 8;
  f32x4 acc[2];
  acc[0] = (f32x4){0.f, 0.f, 0.f, 0.f};
  acc[1] = (f32x4){0.f, 0.f, 0.f, 0.f};

  #pragma unroll
  for (int ks = 0; ks < 4; ++ks) {
    float4 v0 = *reinterpret_cast<const float4*>(xp + ks * 32);
    float4 v1 = *reinterpret_cast<const float4*>(xp + ks * 32 + 4);
    bf16x8 a;
    a[0] = (__bf16)v0.x; a[1] = (__bf16)v0.y; a[2] = (__bf16)v0.z; a[3] = (__bf16)v0.w;
    a[4] = (__bf16)v1.x; a[5] = (__bf16)v1.y; a[6] = (__bf16)v1.z; a[7] = (__bf16)v1.w;
    acc[0] = __builtin_amdgcn_mfma_f32_16x16x32_bf16(a, bw[0][ks], acc[0], 0, 0, 0);
    acc[1] = __builtin_amdgcn_mfma_f32_16x16x32_bf16(a, bw[1][ks], acc[1], 0, 0, 0);
  }

  #pragma unroll
  for (int r = 0; r < 4; ++r) {
    long rr = r0 + lhi * 4 + r;
    float dv = dinv[rr >> 3];
    hs[rr * 32 + l15]      = __float2bfloat16(acc[0][r] * dv);
    hs[rr * 32 + 16 + l15] = __float2bfloat16(acc[1][r] * dv);
  }
}

// ---------------- K2: fused prep + degree count + hs dummy-row zero ----------------
__global__ __launch_bounds__(256) void k_prep_count(
    const int* __restrict__ col, int* __restrict__ cnt, int E,
    const float* __restrict__ Wih, const float* __restrict__ Whh,
    const float* __restrict__ bih, const float* __restrict__ bhh,
    const float* __restrict__ fc1W, const float* __restrict__ fc2W,
    const float* __restrict__ convW, const float* __restrict__ gcnW,
    __hip_bfloat16* __restrict__ Wcat, float* __restrict__ bias,
    __hip_bfloat16* __restrict__ W1b, __hip_bfloat16* __restrict__ W2b,
    __hip_bfloat16* __restrict__ Wcb, __hip_bfloat16* __restrict__ Wgt,
    unsigned int* __restrict__ hz)
{
  int i = blockIdx.x * 256 + threadIdx.x;
  if (i < E) atomicAdd(&cnt[col[i]], 1);
  if (i < 128) hz[i] = 0u;
  if (i < 512 * 192) {
    int q = i / 192, k = i - q * 192;
    float v = (k < 64) ? Wih[q * 64 + k] : Whh[q * 128 + (k - 64)];
    Wcat[i] = __float2bfloat16(v);
  } else if (i < 512 * 192 + 64 * 128) {
    int j = i - 512 * 192;
    W1b[j] = __float2bfloat16(fc1W[j]);
  } else if (i < 512 * 192 + 64 * 128 + 128 * 64) {
    int j = i - 512 * 192 - 64 * 128;
    W2b[j] = __float2bfloat16(fc2W[j]);
  } else if (i < 512 * 192 + 64 * 128 + 128 * 64 + 64 * 64) {
    int j = i - 512 * 192 - 64 * 128 - 128 * 64;
    Wcb[j] = __float2bfloat16(convW[j]);
  } else if (i < 512 * 192 + 64 * 128 + 128 * 64 + 64 * 64 + 32 * 128) {
    int j = i - 512 * 192 - 64 * 128 - 128 * 64 - 64 * 64;
    int o = j >> 7, f = j & 127;                  // Wgt[o][f] = gcnW[f][o]
    Wgt[j] = __float2bfloat16(gcnW[f * 32 + o]);
  } else if (i < PREP_TOT) {
    int j = i - (PREP_TOT - 512);
    bias[j] = bih[j] + bhh[j];
  }
}

// ---------------- K3: vectorized single-block scan (shuffle-based, 2 barriers) ----------------
// cnt is padded+zeroed to 1024*CH ints, so loads need no guards. All per-thread
// arrays statically indexed (unrolled with compile-time q, runtime CH guard).
__global__ __launch_bounds__(1024) void k_scan(const int* __restrict__ cnt,
                                               int* __restrict__ row_ptr,
                                               int* __restrict__ cursor,
                                               float* __restrict__ dinv, int N)
{
  __shared__ int wsum[16];
  int tid  = threadIdx.x;
  int lane = tid & 63;
  int wid  = tid >> 6;
  const int CH = (N + 1023) >> 10;     // <= 32 assumed (20 for N=20000)
  const int nv = (CH + 3) >> 2;
  int i0 = tid * CH;

  int vals[32];
  #pragma unroll
  for (int q = 0; q < 8; ++q) {
    if (q < nv) {
      int4 v = *reinterpret_cast<const int4*>(cnt + i0 + q * 4);
      vals[q * 4 + 0] = v.x; vals[q * 4 + 1] = v.y;
      vals[q * 4 + 2] = v.z; vals[q * 4 + 3] = v.w;
    }
  }
  int sum = 0;
  #pragma unroll
  for (int j = 0; j < 32; ++j) if (j < CH) sum += vals[j];

  // wave-level inclusive scan
  int v = sum;
  #pragma unroll
  for (int off = 1; off < 64; off <<= 1) {
    int t = __shfl_up(v, off);
    if (lane >= off) v += t;
  }
  if (lane == 63) wsum[wid] = v;
  __syncthreads();
  if (wid == 0) {
    int w = (lane < 16) ? wsum[lane] : 0;
    #pragma unroll
    for (int off = 1; off < 16; off <<= 1) {
      int t = __shfl_up(w, off);
      if (lane >= off) w += t;
    }
    if (lane < 16) wsum[lane] = w;
  }
  __syncthreads();

  int run = v - sum + ((wid > 0) ? wsum[wid - 1] : 0);   // exclusive prefix
  if (i0 < N) {
    int rp[32], cu[32]; float dv[32];
    #pragma unroll
    for (int q = 0; q < 32; ++q) {
      if (q < CH) {
        int c = vals[q];
        rp[q] = run; cu[q] = run;
        dv[q] = rsqrtf((float)c + 1.0f);
        run += c;
      }
    }
    #pragma unroll
    for (int q = 0; q < 8; ++q) {
      if (q < nv) {
        *reinterpret_cast<int4*>(row_ptr + i0 + q * 4) =
            make_int4(rp[q*4], rp[q*4+1], rp[q*4+2], rp[q*4+3]);
        *reinterpret_cast<int4*>(cursor + i0 + q * 4) =
            make_int4(cu[q*4], cu[q*4+1], cu[q*4+2], cu[q*4+3]);
        *reinterpret_cast<float4*>(dinv + i0 + q * 4) =
            make_float4(dv[q*4], dv[q*4+1], dv[q*4+2], dv[q*4+3]);
      }
    }
    if (i0 + CH >= N) row_ptr[N] = run;
  }
}

// ---------------- gather helper: 16-slot batch with select-tail (no padding) ----------------
__device__ __forceinline__ void gat16(const int* __restrict__ adj, int base, int end, int NN,
                                      const __hip_bfloat16* __restrict__ hl,
                                      float& a0, float& a1, float& a2, float& a3)
{
  int lim = end - base;
  int s0 = adj[base + 0],  s1 = adj[base + 1],  s2 = adj[base + 2],  s3 = adj[base + 3];
  int s4 = adj[base + 4],  s5 = adj[base + 5],  s6 = adj[base + 6],  s7 = adj[base + 7];
  int s8 = adj[base + 8],  s9 = adj[base + 9],  sa = adj[base + 10], sb = adj[base + 11];
  int sc = adj[base + 12], sd = adj[base + 13], se = adj[base + 14], sf = adj[base + 15];
  s0 = (0  < lim) ? s0 : NN;  s1 = (1  < lim) ? s1 : NN;
  s2 = (2  < lim) ? s2 : NN;  s3 = (3  < lim) ? s3 : NN;
  s4 = (4  < lim) ? s4 : NN;  s5 = (5  < lim) ? s5 : NN;
  s6 = (6  < lim) ? s6 : NN;  s7 = (7  < lim) ? s7 : NN;
  s8 = (8  < lim) ? s8 : NN;  s9 = (9  < lim) ? s9 : NN;
  sa = (10 < lim) ? sa : NN;  sb = (11 < lim) ? sb : NN;
  sc = (12 < lim) ? sc : NN;  sd = (13 < lim) ? sd : NN;
  se = (14 < lim) ? se : NN;  sf = (15 < lim) ? sf : NN;
  ushort4 r0 = *reinterpret_cast<const ushort4*>(hl + (size_t)s0 * 256);
  ushort4 r1 = *reinterpret_cast<const ushort4*>(hl + (size_t)s1 * 256);
  ushort4 r2 = *reinterpret_cast<const ushort4*>(hl + (size_t)s2 * 256);
  ushort4 r3 = *reinterpret_cast<const ushort4*>(hl + (size_t)s3 * 256);
  ushort4 r4 = *reinterpret_cast<const ushort4*>(hl + (size_t)s4 * 256);
  ushort4 r5 = *reinterpret_cast<const ushort4*>(hl + (size_t)s5 * 256);
  ushort4 r6 = *reinterpret_cast<const ushort4*>(hl + (size_t)s6 * 256);
  ushort4 r7 = *reinterpret_cast<const ushort4*>(hl + (size_t)s7 * 256);
  ushort4 r8 = *reinterpret_cast<const ushort4*>(hl + (size_t)s8 * 256);
  ushort4 r9 = *reinterpret_cast<const ushort4*>(hl + (size_t)s9 * 256);
  ushort4 ra = *reinterpret_cast<const ushort4*>(hl + (size_t)sa * 256);
  ushort4 rb = *reinterpret_cast<const ushort4*>(hl + (size_t)sb * 256);
  ushort4 rc = *reinterpret_cast<const ushort4*>(hl + (size_t)sc * 256);
  ushort4 rd = *reinterpret_cast<const ushort4*>(hl + (size_t)sd * 256);
  ushort4 re = *reinterpret_cast<const ushort4*>(hl + (size_t)se * 256);
  ushort4 rf = *reinterpret_cast<const ushort4*>(hl + (size_t)sf * 256);
  a0 += ((ubf(r0.x) + ubf(r1.x)) + (ubf(r2.x) + ubf(r3.x))) + ((ubf(r4.x) + ubf(r5.x)) + (ubf(r6.x) + ubf(r7.x)))
      + ((ubf(r8.x) + ubf(r9.x)) + (ubf(ra.x) + ubf(rb.x))) + ((ubf(rc.x) + ubf(rd.x)) + (ubf(re.x) + ubf(rf.x)));
  a1 += ((ubf(r0.y) + ubf(r1.y)) + (ubf(r2.y) + ubf(r3.y))) + ((ubf(r4.y) + ubf(r5.y)) + (ubf(r6.y) + ubf(r7.y)))
      + ((ubf(r8.y) + ubf(r9.y)) + (ubf(ra.y) + ubf(rb.y))) + ((ubf(rc.y) + ubf(rd.y)) + (ubf(re.y) + ubf(rf.y)));
  a2 += ((ubf(r0.z) + ubf(r1.z)) + (ubf(r2.z) + ubf(r3.z))) + ((ubf(r4.z) + ubf(r5.z)) + (ubf(r6.z) + ubf(r7.z)))
      + ((ubf(r8.z) + ubf(r9.z)) + (ubf(ra.z) + ubf(rb.z))) + ((ubf(rc.z) + ubf(rd.z)) + (ubf(re.z) + ubf(rf.z)));
  a3 += ((ubf(r0.w) + ubf(r1.w)) + (ubf(r2.w) + ubf(r3.w))) + ((ubf(r4.w) + ubf(r5.w)) + (ubf(r6.w) + ubf(r7.w)))
      + ((ubf(r8.w) + ubf(r9.w)) + (ubf(ra.w) + ubf(rb.w))) + ((ubf(rc.w) + ubf(rd.w)) + (ubf(re.w) + ubf(rf.w)));
}

// ---------------- K5: FUSED gather (2 nodes/wave, LDS out) + conv MFMA ----------------
__global__ __launch_bounds__(256) void k_gather_conv(
    const int* __restrict__ row_ptr, const int* __restrict__ adj,
    const float* __restrict__ dinv, const __hip_bfloat16* __restrict__ hs,
    const float* __restrict__ gcnb,
    const __hip_bfloat16* __restrict__ Wcb, const float* __restrict__ bc,
    __hip_bfloat16* __restrict__ seq, int N)
{
  __shared__ __hip_bfloat16 g_lds[8 * 256];
  __shared__ __hip_bfloat16 A[4][16][72];
  int tid  = threadIdx.x;
  int wave = tid >> 6;
  int lane = tid & 63;
  int l15  = lane & 15;
  int lhi  = lane >> 4;

  if (tid < 144) {               // zero pad rows 14,15 of each wave-tile
    int w = tid / 36, q = tid % 36;
    int row = 14 + q / 18, cc = (q % 18) * 4;
    *reinterpret_cast<uint2*>(&A[w][row][cc]) = make_uint2(0u, 0u);
  }

  int na = blockIdx.x * 8 + wave * 2;
  int nb = na + 1;
  int pa = row_ptr[na], ea = row_ptr[na + 1];
  int pb = row_ptr[nb], eb = row_ptr[nb + 1];
  float da = dinv[na], db = dinv[nb];

  const __hip_bfloat16* hl = hs + lane * 4;
  float a0, a1, a2, a3, b0, b1, b2, b3;
  {
    ushort4 hva = *reinterpret_cast<const ushort4*>(hl + (size_t)na * 256);
    ushort4 hvb = *reinterpret_cast<const ushort4*>(hl + (size_t)nb * 256);
    a0 = ubf(hva.x); a1 = ubf(hva.y); a2 = ubf(hva.z); a3 = ubf(hva.w);
    b0 = ubf(hvb.x); b1 = ubf(hvb.y); b2 = ubf(hvb.z); b3 = ubf(hvb.w);
  }

  while (pa < ea && pb < eb) {
    gat16(adj, pa, ea, N, hl, a0, a1, a2, a3);
    gat16(adj, pb, eb, N, hl, b0, b1, b2, b3);
    pa += 16; pb += 16;
  }
  while (pa < ea) { gat16(adj, pa, ea, N, hl, a0, a1, a2, a3); pa += 16; }
  while (pb < eb) { gat16(adj, pb, eb, N, hl, b0, b1, b2, b3); pb += 16; }

  int ci0 = (lane * 4) & 31;
  float g0 = gcnb[ci0 + 0], g1 = gcnb[ci0 + 1], g2 = gcnb[ci0 + 2], g3 = gcnb[ci0 + 3];
  ushort4 oa, ob;
  oa.x = bfb(fmaxf(fmaf(a0, da, g0), 0.f));
  oa.y = bfb(fmaxf(fmaf(a1, da, g1), 0.f));
  oa.z = bfb(fmaxf(fmaf(a2, da, g2), 0.f));
  oa.w = bfb(fmaxf(fmaf(a3, da, g3), 0.f));
  ob.x = bfb(fmaxf(fmaf(b0, db, g0), 0.f));
  ob.y = bfb(fmaxf(fmaf(b1, db, g1), 0.f));
  ob.z = bfb(fmaxf(fmaf(b2, db, g2), 0.f));
  ob.w = bfb(fmaxf(fmaf(b3, db, g3), 0.f));
  *reinterpret_cast<ushort4*>(&g_lds[(wave * 2 + 0) * 256 + lane * 4]) = oa;
  *reinterpret_cast<ushort4*>(&g_lds[(wave * 2 + 1) * 256 + lane * 4]) = ob;
  __syncthreads();

  {
    int f0 = tid * 8;
    ushort8v v = *reinterpret_cast<const ushort8v*>(&g_lds[f0]);
    int n_local = f0 >> 8;
    int rem     = f0 & 255;
    int t_row   = rem >> 5;
    int ci      = rem & 31;
    int w       = n_local >> 1;
    int rbase   = (n_local & 1) * 7;
    #pragma unroll
    for (int e = 0; e < 8; ++e) {
      unsigned short u = v[e];
      int k0 = (ci + e) * 2;
      if (t_row <= 6)
        *reinterpret_cast<unsigned short*>(&A[w][rbase + t_row][k0]) = u;
      if (t_row >= 1)
        *reinterpret_cast<unsigned short*>(&A[w][rbase + t_row - 1][k0 + 1]) = u;
    }
  }
  __syncthreads();

  bf16x8 bfr[2][4];
  #pragma unroll
  for (int ks = 0; ks < 2; ++ks)
    #pragma unroll
    for (int cg = 0; cg < 4; ++cg)
      bfr[ks][cg] = load_bf8(Wcb + (cg * 16 + l15) * 64 + ks * 32 + lhi * 8);

  f32x4 acc[4];
  #pragma unroll
  for (int cg = 0; cg < 4; ++cg) acc[cg] = (f32x4){0.f, 0.f, 0.f, 0.f};

  #pragma unroll
  for (int ks = 0; ks < 2; ++ks) {
    bf16x8 a = load_bf8(&A[wave][l15][ks * 32 + lhi * 8]);
    #pragma unroll
    for (int cg = 0; cg < 4; ++cg)
      acc[cg] = __builtin_amdgcn_mfma_f32_16x16x32_bf16(a, bfr[ks][cg], acc[cg], 0, 0, 0);
  }

  long n64 = (long)N * 64;
  #pragma unroll
  for (int r = 0; r < 4; ++r) {
    int rr = lhi * 4 + r;
    if (rr < 14) {
      int hi = rr >= 7 ? 1 : 0;
      int nl = wave * 2 + hi;
      int t  = rr - 7 * hi;
      long n = (long)blockIdx.x * 8 + nl;
      #pragma unroll
      for (int cg = 0; cg < 4; ++cg) {
        int co = cg * 16 + l15;
        seq[(long)t * n64 + n * 64 + co] = __float2bfloat16(fmaxf(acc[cg][r] + bc[co], 0.f));
      }
    }
  }
}

// ---------------- K7: fused 7-step LSTM + head, 80 rows/block (M_rep=5), fast gates ----------------
__global__ __launch_bounds__(512, 2) void k_lstm_head(
    const __hip_bfloat16* __restrict__ seq,   // [7][N][64]
    const __hip_bfloat16* __restrict__ Wcat,  // [512][192]
    const float* __restrict__ bias,           // [512]
    const __hip_bfloat16* __restrict__ W1b,   // [64][128]
    const float* __restrict__ fc1b,
    const __hip_bfloat16* __restrict__ W2b,   // [128][64]
    const float* __restrict__ fc2b,
    float* __restrict__ out, int N)
{
  __shared__ __hip_bfloat16 h_lds[2][80][136];
  __shared__ __hip_bfloat16 s1_lds[80][72];
  int tid  = threadIdx.x;
  int wave = tid >> 6;
  int lane = tid & 63;
  int l15  = lane & 15;
  int lhi  = lane >> 4;
  long n0  = (long)blockIdx.x * 80;
  int hc   = wave * 16 + l15;

  bf16x8 bw[6][4];
  #pragma unroll
  for (int ks = 0; ks < 6; ++ks)
    #pragma unroll
    for (int gg = 0; gg < 4; ++gg)
      bw[ks][gg] = load_bf8(Wcat + (size_t)(gg * 128 + hc) * 192 + ks * 32 + lhi * 8);

  float kbi = bias[hc]       * NL2E;
  float kbf = bias[128 + hc] * NL2E;
  float kbg = bias[256 + hc] * NL2E2;
  float kbo = bias[384 + hc] * NL2E;
  float c[5][4];
  #pragma unroll
  for (int g = 0; g < 5; ++g)
    #pragma unroll
    for (int r = 0; r < 4; ++r) c[g][r] = 0.f;

  size_t tstr = (size_t)N * 64;
  const __hip_bfloat16* spb = seq + (n0 + l15) * 64 + lhi * 8;

  for (int t = 0; t < 7; ++t) {
    f32x4 acc[5][4];
    #pragma unroll
    for (int g = 0; g < 5; ++g)
      #pragma unroll
      for (int gg = 0; gg < 4; ++gg)
        acc[g][gg] = (f32x4){0.f, 0.f, 0.f, 0.f};

    #pragma unroll
    for (int g = 0; g < 5; ++g) {
      const __hip_bfloat16* sp = spb + (size_t)t * tstr + (size_t)g * 16 * 64;
      bf16x8 a0 = load_bf8(sp);
      bf16x8 a1 = load_bf8(sp + 32);
      #pragma unroll
      for (int gg = 0; gg < 4; ++gg)
        acc[g][gg] = __builtin_amdgcn_mfma_f32_16x16x32_bf16(a0, bw[0][gg], acc[g][gg], 0, 0, 0);
      #pragma unroll
      for (int gg = 0; gg < 4; ++gg)
        acc[g][gg] = __builtin_amdgcn_mfma_f32_16x16x32_bf16(a1, bw[1][gg], acc[g][gg], 0, 0, 0);
    }

    if (t > 0) {
      const __hip_bfloat16* hb = &h_lds[(t + 1) & 1][0][0];
      #pragma unroll
      for (int ks = 2; ks < 6; ++ks) {
        #pragma unroll
        for (int g = 0; g < 5; ++g) {
          bf16x8 a = load_bf8(hb + (g * 16 + l15) * 136 + (ks - 2) * 32 + lhi * 8);
          #pragma unroll
          for (int gg = 0; gg < 4; ++gg)
            acc[g][gg] = __builtin_amdgcn_mfma_f32_16x16x32_bf16(a, bw[ks][gg], acc[g][gg], 0, 0, 0);
        }
      }
    }

    __hip_bfloat16* hw = &h_lds[t & 1][0][0];
    #pragma unroll
    for (int g = 0; g < 5; ++g) {
      #pragma unroll
      for (int r = 0; r < 4; ++r) {
        float si  = rcp_f(1.f + exp2_f(fmaf(acc[g][0][r], NL2E,  kbi)));
        float sf  = rcp_f(1.f + exp2_f(fmaf(acc[g][1][r], NL2E,  kbf)));
        float sg2 = rcp_f(1.f + exp2_f(fmaf(acc[g][2][r], NL2E2, kbg)));
        float so  = rcp_f(1.f + exp2_f(fmaf(acc[g][3][r], NL2E,  kbo)));
        float tg  = fmaf(2.f, sg2, -1.f);
        float cn  = fmaf(sf, c[g][r], si * tg);
        c[g][r] = cn;
        float sc2 = rcp_f(1.f + exp2_f(cn * NL2E2));
        hw[(g * 16 + lhi * 4 + r) * 136 + hc] = __float2bfloat16(so * fmaf(2.f, sc2, -1.f));
      }
    }
    __syncthreads();
  }

  if (wave < 4) {
    int col1 = wave * 16 + l15;
    float b1 = fc1b[col1];
    #pragma unroll
    for (int g = 0; g < 5; ++g) {
      f32x4 acc1v = (f32x4){0.f, 0.f, 0.f, 0.f};
      #pragma unroll
      for (int ks = 0; ks < 4; ++ks) {
        int kb = ks * 32 + lhi * 8;
        bf16x8 a = load_bf8(&h_lds[0][g * 16 + l15][kb]);
        bf16x8 b = load_bf8(W1b + col1 * 128 + kb);
        acc1v = __builtin_amdgcn_mfma_f32_16x16x32_bf16(a, b, acc1v, 0, 0, 0);
      }
      #pragma unroll
      for (int r = 0; r < 4; ++r)
        s1_lds[g * 16 + lhi * 4 + r][col1] = __float2bfloat16(fmaxf(acc1v[r] + b1, 0.f));
    }
  }
  __syncthreads();

  {
    int c2 = wave * 16 + l15;
    float b2 = fc2b[c2];
    #pragma unroll
    for (int g = 0; g < 5; ++g) {
      f32x4 acc2 = (f32x4){0.f, 0.f, 0.f, 0.f};
      #pragma unroll
      for (int ks = 0; ks < 2; ++ks) {
        int kb = ks * 32 + lhi * 8;
        bf16x8 a = load_bf8(&s1_lds[g * 16 + l15][kb]);
        bf16x8 b = load_bf8(W2b + c2 * 64 + kb);
        acc2 = __builtin_amdgcn_mfma_f32_16x16x32_bf16(a, b, acc2, 0, 0, 0);
      }
      #pragma unroll
      for (int r = 0; r < 4; ++r)
        out[(n0 + g * 16 + lhi * 4 + r) * 128 + c2] = sigm_fast(acc2[r] + b2);
    }
  }
}

extern "C" void kernel_launch(void* const* d_in, const int* in_sizes, int n_in,
                              void* d_out, int out_size, void* d_ws, size_t ws_size,
                              hipStream_t stream)
{
  const float* x     = (const float*)d_in[0];
  const int*   ei    = (const int*)d_in[1];
  const float* gcnW  = (const float*)d_in[2];
  const float* gcnb  = (const float*)d_in[3];
  const float* convW = (const float*)d_in[4];
  const float* convb = (const float*)d_in[5];
  const float* Wih   = (const float*)d_in[6];
  const float* Whh   = (const float*)d_in[7];
  const float* bih   = (const float*)d_in[8];
  const float* bhh   = (const float*)d_in[9];
  const float* fc1W  = (const float*)d_in[10];
  const float* fc1b  = (const float*)d_in[11];
  const float* fc2W  = (const float*)d_in[12];
  const float* fc2b  = (const float*)d_in[13];

  const int N = in_sizes[0] / (T_STEPS * F_IN);
  const int E = in_sizes[1] / 2;
  const int CH = (N + 1023) >> 10;
  const int cntPad = 1024 * CH;        // padded cnt length for vector scan

  char* ws = (char*)d_ws;
  size_t off = 0;
  auto alloc = [&](size_t bytes) {
    void* p = ws + off;
    off = (off + bytes + 255) & ~(size_t)255;
    return p;
  };
  __hip_bfloat16* hs  = (__hip_bfloat16*)alloc((size_t)(N + 1) * 256 * 2); // [N+1][256], row N zeros
  __hip_bfloat16* seq = (__hip_bfloat16*)alloc((size_t)7 * N * 64 * 2);
  int* cnt     = (int*)alloc((size_t)cntPad * 4);
  int* row_ptr = (int*)alloc((size_t)(N + 4) * 4);
  int* cursor  = (int*)alloc((size_t)(N + 4) * 4);
  float* dinv  = (float*)alloc((size_t)(N + 4) * 4);
  int* adj     = (int*)alloc((size_t)(E + 16) * 4);   // +16 slack (select-tail)
  __hip_bfloat16* Wcat = (__hip_bfloat16*)alloc(512 * 192 * 2);
  float* bias = (float*)alloc(512 * 4);
  __hip_bfloat16* W1b = (__hip_bfloat16*)alloc(64 * 128 * 2);
  __hip_bfloat16* W2b = (__hip_bfloat16*)alloc(128 * 64 * 2);
  __hip_bfloat16* Wcb = (__hip_bfloat16*)alloc(64 * 64 * 2);
  __hip_bfloat16* Wgt = (__hip_bfloat16*)alloc(32 * 128 * 2);

  hipMemsetAsync(cnt, 0, (size_t)cntPad * 4, stream);

  int pc_work = E > PREP_TOT ? E : PREP_TOT;
  k_prep_count<<<(pc_work + 255) / 256, 256, 0, stream>>>(
      ei + E, cnt, E, Wih, Whh, bih, bhh, fc1W, fc2W, convW, gcnW,
      Wcat, bias, W1b, W2b, Wcb, Wgt, (unsigned int*)(hs + (size_t)N * 256));
  k_scan<<<1, 1024, 0, stream>>>(cnt, row_ptr, cursor, dinv, N);
  k_transform_fill<<<(N * T_STEPS) / 64, 256, 0, stream>>>(x, Wgt, dinv, hs, ei, cursor, adj, E);
  k_gather_conv<<<N / 8, 256, 0, stream>>>(row_ptr, adj, dinv, hs, gcnb, Wcb, convb, seq, N);
  k_lstm_head<<<N / 80, 512, 0, stream>>>(seq, Wcat, bias, W1b, fc1b, W2b, fc2b, (float*)d_out, N);
}

// Round 20
// 197.951 us; speedup vs baseline: 2.4794x; 2.4794x over previous
//
#include <hip/hip_runtime.h>
#include <hip/hip_bf16.h>

#define T_STEPS 8
#define F_IN    128
#define H_GCN   32
#define H_CONV  64
#define H_LSTM  128

typedef __bf16 bf16x8 __attribute__((ext_vector_type(8)));
typedef float  f32x4  __attribute__((ext_vector_type(4)));
typedef unsigned short ushort8v __attribute__((ext_vector_type(8)));

#if __has_builtin(__builtin_amdgcn_exp2f)
__device__ __forceinline__ float exp2_f(float x) { return __builtin_amdgcn_exp2f(x); }
#else
__device__ __forceinline__ float exp2_f(float x) { return exp2f(x); }
#endif
#if __has_builtin(__builtin_amdgcn_rcpf)
__device__ __forceinline__ float rcp_f(float x) { return __builtin_amdgcn_rcpf(x); }
#else
__device__ __forceinline__ float rcp_f(float x) { return 1.f / x; }
#endif

#define NL2E  (-1.442695041f)   // -log2(e)
#define NL2E2 (-2.885390082f)   // -2*log2(e)

__device__ __forceinline__ float sigm_fast(float x) {
  return rcp_f(1.f + exp2_f(x * NL2E));
}

__device__ __forceinline__ float ubf(unsigned short u) {
  union { unsigned int i; float f; } v; v.i = ((unsigned int)u) << 16; return v.f;
}
__device__ __forceinline__ unsigned short bfb(float f) {
  __hip_bfloat16 b = __float2bfloat16(f);
  return __builtin_bit_cast(unsigned short, b);
}

__device__ __forceinline__ bf16x8 load_bf8(const __hip_bfloat16* p) {
  int4 v = *reinterpret_cast<const int4*>(p);
  return __builtin_bit_cast(bf16x8, v);
}

#define PREP_TOT (512*192 + 64*128 + 128*64 + 64*64 + 32*128 + 512)

// ---------------- K1: MFMA transform + adjacency fill (fused) ----------------
__global__ __launch_bounds__(256) void k_transform_fill(
    const float* __restrict__ x,
    const __hip_bfloat16* __restrict__ Wgt, // [32][128]
    const float* __restrict__ dinv,
    __hip_bfloat16* __restrict__ hs,
    const int* __restrict__ ei, int* __restrict__ cursor,
    int* __restrict__ adj, int E)
{
  int tid  = threadIdx.x;

  // fill: 640K threads >= E; atomic latency overlaps MFMA below
  {
    int e = blockIdx.x * 256 + tid;
    if (e < E) {
      int r = ei[e], ctg = ei[E + e];
      int pos = atomicAdd(&cursor[ctg], 1);
      adj[pos] = r;
    }
  }

  int wave = tid >> 6;
  int lane = tid & 63;
  int l15  = lane & 15;
  int lhi  = lane >> 4;
  long r0  = (long)blockIdx.x * 64 + wave * 16;

  bf16x8 bw[2][4];
  #pragma unroll
  for (int ct = 0; ct < 2; ++ct)
    #pragma unroll
    for (int ks = 0; ks < 4; ++ks)
      bw[ct][ks] = load_bf8(Wgt + (ct * 16 + l15) * 128 + ks * 32 + lhi * 8);

  const float* xp = x + (r0 + l15) * 128 + lhi * 8;
  f32x4 acc[2];
  acc[0] = (f32x4){0.f, 0.f, 0.f, 0.f};
  acc[1] = (f32x4){0.f, 0.f, 0.f, 0.f};

  #pragma unroll
  for (int ks = 0; ks < 4; ++ks) {
    float4 v0 = *reinterpret_cast<const float4*>(xp + ks * 32);
    float4 v1 = *reinterpret_cast<const float4*>(xp + ks * 32 + 4);
    bf16x8 a;
    a[0] = (__bf16)v0.x; a[1] = (__bf16)v0.y; a[2] = (__bf16)v0.z; a[3] = (__bf16)v0.w;
    a[4] = (__bf16)v1.x; a[5] = (__bf16)v1.y; a[6] = (__bf16)v1.z; a[7] = (__bf16)v1.w;
    acc[0] = __builtin_amdgcn_mfma_f32_16x16x32_bf16(a, bw[0][ks], acc[0], 0, 0, 0);
    acc[1] = __builtin_amdgcn_mfma_f32_16x16x32_bf16(a, bw[1][ks], acc[1], 0, 0, 0);
  }

  #pragma unroll
  for (int r = 0; r < 4; ++r) {
    long rr = r0 + lhi * 4 + r;
    float dv = dinv[rr >> 3];
    hs[rr * 32 + l15]      = __float2bfloat16(acc[0][r] * dv);
    hs[rr * 32 + 16 + l15] = __float2bfloat16(acc[1][r] * dv);
  }
}

// ---------------- K2: fused prep + degree count + hs dummy-row zero ----------------
__global__ __launch_bounds__(256) void k_prep_count(
    const int* __restrict__ col, int* __restrict__ cnt, int E,
    const float* __restrict__ Wih, const float* __restrict__ Whh,
    const float* __restrict__ bih, const float* __restrict__ bhh,
    const float* __restrict__ fc1W, const float* __restrict__ fc2W,
    const float* __restrict__ convW, const float* __restrict__ gcnW,
    __hip_bfloat16* __restrict__ Wcat, float* __restrict__ bias,
    __hip_bfloat16* __restrict__ W1b, __hip_bfloat16* __restrict__ W2b,
    __hip_bfloat16* __restrict__ Wcb, __hip_bfloat16* __restrict__ Wgt,
    unsigned int* __restrict__ hz)
{
  int i = blockIdx.x * 256 + threadIdx.x;
  if (i < E) atomicAdd(&cnt[col[i]], 1);
  if (i < 128) hz[i] = 0u;
  if (i < 512 * 192) {
    int q = i / 192, k = i - q * 192;
    float v = (k < 64) ? Wih[q * 64 + k] : Whh[q * 128 + (k - 64)];
    Wcat[i] = __float2bfloat16(v);
  } else if (i < 512 * 192 + 64 * 128) {
    int j = i - 512 * 192;
    W1b[j] = __float2bfloat16(fc1W[j]);
  } else if (i < 512 * 192 + 64 * 128 + 128 * 64) {
    int j = i - 512 * 192 - 64 * 128;
    W2b[j] = __float2bfloat16(fc2W[j]);
  } else if (i < 512 * 192 + 64 * 128 + 128 * 64 + 64 * 64) {
    int j = i - 512 * 192 - 64 * 128 - 128 * 64;
    Wcb[j] = __float2bfloat16(convW[j]);
  } else if (i < 512 * 192 + 64 * 128 + 128 * 64 + 64 * 64 + 32 * 128) {
    int j = i - 512 * 192 - 64 * 128 - 128 * 64 - 64 * 64;
    int o = j >> 7, f = j & 127;                  // Wgt[o][f] = gcnW[f][o]
    Wgt[j] = __float2bfloat16(gcnW[f * 32 + o]);
  } else if (i < PREP_TOT) {
    int j = i - (PREP_TOT - 512);
    bias[j] = bih[j] + bhh[j];
  }
}

// ---------------- K3: exact scan (proven LDS version, no big per-thread arrays) ----------------
__global__ __launch_bounds__(1024) void k_scan(const int* __restrict__ cnt,
                                               int* __restrict__ row_ptr,
                                               int* __restrict__ cursor,
                                               float* __restrict__ dinv, int N)
{
  __shared__ int s[1024];
  int tid = threadIdx.x;
  const int CH = (N + 1023) >> 10;
  int i0 = tid * CH;
  int sum = 0;
  for (int j = 0; j < CH; ++j) {
    int i = i0 + j;
    if (i < N) sum += cnt[i];
  }
  s[tid] = sum;
  __syncthreads();
  #pragma unroll
  for (int off = 1; off < 1024; off <<= 1) {
    int t = (tid >= off) ? s[tid - off] : 0;
    __syncthreads();
    s[tid] += t;
    __syncthreads();
  }
  int run = (tid > 0) ? s[tid - 1] : 0;
  for (int j = 0; j < CH; ++j) {
    int i = i0 + j;
    if (i < N) {
      int v = cnt[i];
      cursor[i] = run;
      row_ptr[i] = run;
      dinv[i] = rsqrtf((float)v + 1.0f);
      run += v;
      if (i == N - 1) row_ptr[N] = run;
    }
  }
}

// ---------------- gather helper: 16-slot batch with select-tail (no padding) ----------------
__device__ __forceinline__ void gat16(const int* __restrict__ adj, int base, int end, int NN,
                                      const __hip_bfloat16* __restrict__ hl,
                                      float& a0, float& a1, float& a2, float& a3)
{
  int lim = end - base;
  int s0 = adj[base + 0],  s1 = adj[base + 1],  s2 = adj[base + 2],  s3 = adj[base + 3];
  int s4 = adj[base + 4],  s5 = adj[base + 5],  s6 = adj[base + 6],  s7 = adj[base + 7];
  int s8 = adj[base + 8],  s9 = adj[base + 9],  sa = adj[base + 10], sb = adj[base + 11];
  int sc = adj[base + 12], sd = adj[base + 13], se = adj[base + 14], sf = adj[base + 15];
  s0 = (0  < lim) ? s0 : NN;  s1 = (1  < lim) ? s1 : NN;
  s2 = (2  < lim) ? s2 : NN;  s3 = (3  < lim) ? s3 : NN;
  s4 = (4  < lim) ? s4 : NN;  s5 = (5  < lim) ? s5 : NN;
  s6 = (6  < lim) ? s6 : NN;  s7 = (7  < lim) ? s7 : NN;
  s8 = (8  < lim) ? s8 : NN;  s9 = (9  < lim) ? s9 : NN;
  sa = (10 < lim) ? sa : NN;  sb = (11 < lim) ? sb : NN;
  sc = (12 < lim) ? sc : NN;  sd = (13 < lim) ? sd : NN;
  se = (14 < lim) ? se : NN;  sf = (15 < lim) ? sf : NN;
  ushort4 r0 = *reinterpret_cast<const ushort4*>(hl + (size_t)s0 * 256);
  ushort4 r1 = *reinterpret_cast<const ushort4*>(hl + (size_t)s1 * 256);
  ushort4 r2 = *reinterpret_cast<const ushort4*>(hl + (size_t)s2 * 256);
  ushort4 r3 = *reinterpret_cast<const ushort4*>(hl + (size_t)s3 * 256);
  ushort4 r4 = *reinterpret_cast<const ushort4*>(hl + (size_t)s4 * 256);
  ushort4 r5 = *reinterpret_cast<const ushort4*>(hl + (size_t)s5 * 256);
  ushort4 r6 = *reinterpret_cast<const ushort4*>(hl + (size_t)s6 * 256);
  ushort4 r7 = *reinterpret_cast<const ushort4*>(hl + (size_t)s7 * 256);
  ushort4 r8 = *reinterpret_cast<const ushort4*>(hl + (size_t)s8 * 256);
  ushort4 r9 = *reinterpret_cast<const ushort4*>(hl + (size_t)s9 * 256);
  ushort4 ra = *reinterpret_cast<const ushort4*>(hl + (size_t)sa * 256);
  ushort4 rb = *reinterpret_cast<const ushort4*>(hl + (size_t)sb * 256);
  ushort4 rc = *reinterpret_cast<const ushort4*>(hl + (size_t)sc * 256);
  ushort4 rd = *reinterpret_cast<const ushort4*>(hl + (size_t)sd * 256);
  ushort4 re = *reinterpret_cast<const ushort4*>(hl + (size_t)se * 256);
  ushort4 rf = *reinterpret_cast<const ushort4*>(hl + (size_t)sf * 256);
  a0 += ((ubf(r0.x) + ubf(r1.x)) + (ubf(r2.x) + ubf(r3.x))) + ((ubf(r4.x) + ubf(r5.x)) + (ubf(r6.x) + ubf(r7.x)))
      + ((ubf(r8.x) + ubf(r9.x)) + (ubf(ra.x) + ubf(rb.x))) + ((ubf(rc.x) + ubf(rd.x)) + (ubf(re.x) + ubf(rf.x)));
  a1 += ((ubf(r0.y) + ubf(r1.y)) + (ubf(r2.y) + ubf(r3.y))) + ((ubf(r4.y) + ubf(r5.y)) + (ubf(r6.y) + ubf(r7.y)))
      + ((ubf(r8.y) + ubf(r9.y)) + (ubf(ra.y) + ubf(rb.y))) + ((ubf(rc.y) + ubf(rd.y)) + (ubf(re.y) + ubf(rf.y)));
  a2 += ((ubf(r0.z) + ubf(r1.z)) + (ubf(r2.z) + ubf(r3.z))) + ((ubf(r4.z) + ubf(r5.z)) + (ubf(r6.z) + ubf(r7.z)))
      + ((ubf(r8.z) + ubf(r9.z)) + (ubf(ra.z) + ubf(rb.z))) + ((ubf(rc.z) + ubf(rd.z)) + (ubf(re.z) + ubf(rf.z)));
  a3 += ((ubf(r0.w) + ubf(r1.w)) + (ubf(r2.w) + ubf(r3.w))) + ((ubf(r4.w) + ubf(r5.w)) + (ubf(r6.w) + ubf(r7.w)))
      + ((ubf(r8.w) + ubf(r9.w)) + (ubf(ra.w) + ubf(rb.w))) + ((ubf(rc.w) + ubf(rd.w)) + (ubf(re.w) + ubf(rf.w)));
}

// ---------------- K5: FUSED gather (2 nodes/wave, LDS out) + conv MFMA ----------------
__global__ __launch_bounds__(256) void k_gather_conv(
    const int* __restrict__ row_ptr, const int* __restrict__ adj,
    const float* __restrict__ dinv, const __hip_bfloat16* __restrict__ hs,
    const float* __restrict__ gcnb,
    const __hip_bfloat16* __restrict__ Wcb, const float* __restrict__ bc,
    __hip_bfloat16* __restrict__ seq, int N)
{
  __shared__ __hip_bfloat16 g_lds[8 * 256];
  __shared__ __hip_bfloat16 A[4][16][72];
  int tid  = threadIdx.x;
  int wave = tid >> 6;
  int lane = tid & 63;
  int l15  = lane & 15;
  int lhi  = lane >> 4;

  if (tid < 144) {               // zero pad rows 14,15 of each wave-tile
    int w = tid / 36, q = tid % 36;
    int row = 14 + q / 18, cc = (q % 18) * 4;
    *reinterpret_cast<uint2*>(&A[w][row][cc]) = make_uint2(0u, 0u);
  }

  int na = blockIdx.x * 8 + wave * 2;
  int nb = na + 1;
  int pa = row_ptr[na], ea = row_ptr[na + 1];
  int pb = row_ptr[nb], eb = row_ptr[nb + 1];
  float da = dinv[na], db = dinv[nb];

  const __hip_bfloat16* hl = hs + lane * 4;
  float a0, a1, a2, a3, b0, b1, b2, b3;
  {
    ushort4 hva = *reinterpret_cast<const ushort4*>(hl + (size_t)na * 256);
    ushort4 hvb = *reinterpret_cast<const ushort4*>(hl + (size_t)nb * 256);
    a0 = ubf(hva.x); a1 = ubf(hva.y); a2 = ubf(hva.z); a3 = ubf(hva.w);
    b0 = ubf(hvb.x); b1 = ubf(hvb.y); b2 = ubf(hvb.z); b3 = ubf(hvb.w);
  }

  while (pa < ea && pb < eb) {
    gat16(adj, pa, ea, N, hl, a0, a1, a2, a3);
    gat16(adj, pb, eb, N, hl, b0, b1, b2, b3);
    pa += 16; pb += 16;
  }
  while (pa < ea) { gat16(adj, pa, ea, N, hl, a0, a1, a2, a3); pa += 16; }
  while (pb < eb) { gat16(adj, pb, eb, N, hl, b0, b1, b2, b3); pb += 16; }

  int ci0 = (lane * 4) & 31;
  float g0 = gcnb[ci0 + 0], g1 = gcnb[ci0 + 1], g2 = gcnb[ci0 + 2], g3 = gcnb[ci0 + 3];
  ushort4 oa, ob;
  oa.x = bfb(fmaxf(fmaf(a0, da, g0), 0.f));
  oa.y = bfb(fmaxf(fmaf(a1, da, g1), 0.f));
  oa.z = bfb(fmaxf(fmaf(a2, da, g2), 0.f));
  oa.w = bfb(fmaxf(fmaf(a3, da, g3), 0.f));
  ob.x = bfb(fmaxf(fmaf(b0, db, g0), 0.f));
  ob.y = bfb(fmaxf(fmaf(b1, db, g1), 0.f));
  ob.z = bfb(fmaxf(fmaf(b2, db, g2), 0.f));
  ob.w = bfb(fmaxf(fmaf(b3, db, g3), 0.f));
  *reinterpret_cast<ushort4*>(&g_lds[(wave * 2 + 0) * 256 + lane * 4]) = oa;
  *reinterpret_cast<ushort4*>(&g_lds[(wave * 2 + 1) * 256 + lane * 4]) = ob;
  __syncthreads();

  {
    int f0 = tid * 8;
    ushort8v v = *reinterpret_cast<const ushort8v*>(&g_lds[f0]);
    int n_local = f0 >> 8;
    int rem     = f0 & 255;
    int t_row   = rem >> 5;
    int ci      = rem & 31;
    int w       = n_local >> 1;
    int rbase   = (n_local & 1) * 7;
    #pragma unroll
    for (int e = 0; e < 8; ++e) {
      unsigned short u = v[e];
      int k0 = (ci + e) * 2;
      if (t_row <= 6)
        *reinterpret_cast<unsigned short*>(&A[w][rbase + t_row][k0]) = u;
      if (t_row >= 1)
        *reinterpret_cast<unsigned short*>(&A[w][rbase + t_row - 1][k0 + 1]) = u;
    }
  }
  __syncthreads();

  bf16x8 bfr[2][4];
  #pragma unroll
  for (int ks = 0; ks < 2; ++ks)
    #pragma unroll
    for (int cg = 0; cg < 4; ++cg)
      bfr[ks][cg] = load_bf8(Wcb + (cg * 16 + l15) * 64 + ks * 32 + lhi * 8);

  f32x4 acc[4];
  #pragma unroll
  for (int cg = 0; cg < 4; ++cg) acc[cg] = (f32x4){0.f, 0.f, 0.f, 0.f};

  #pragma unroll
  for (int ks = 0; ks < 2; ++ks) {
    bf16x8 a = load_bf8(&A[wave][l15][ks * 32 + lhi * 8]);
    #pragma unroll
    for (int cg = 0; cg < 4; ++cg)
      acc[cg] = __builtin_amdgcn_mfma_f32_16x16x32_bf16(a, bfr[ks][cg], acc[cg], 0, 0, 0);
  }

  long n64 = (long)N * 64;
  #pragma unroll
  for (int r = 0; r < 4; ++r) {
    int rr = lhi * 4 + r;
    if (rr < 14) {
      int hi = rr >= 7 ? 1 : 0;
      int nl = wave * 2 + hi;
      int t  = rr - 7 * hi;
      long n = (long)blockIdx.x * 8 + nl;
      #pragma unroll
      for (int cg = 0; cg < 4; ++cg) {
        int co = cg * 16 + l15;
        seq[(long)t * n64 + n * 64 + co] = __float2bfloat16(fmaxf(acc[cg][r] + bc[co], 0.f));
      }
    }
  }
}

// ---------------- K7: fused 7-step LSTM + head, 80 rows/block (M_rep=5), fast gates ----------------
__global__ __launch_bounds__(512, 2) void k_lstm_head(
    const __hip_bfloat16* __restrict__ seq,   // [7][N][64]
    const __hip_bfloat16* __restrict__ Wcat,  // [512][192]
    const float* __restrict__ bias,           // [512]
    const __hip_bfloat16* __restrict__ W1b,   // [64][128]
    const float* __restrict__ fc1b,
    const __hip_bfloat16* __restrict__ W2b,   // [128][64]
    const float* __restrict__ fc2b,
    float* __restrict__ out, int N)
{
  __shared__ __hip_bfloat16 h_lds[2][80][136];
  __shared__ __hip_bfloat16 s1_lds[80][72];
  int tid  = threadIdx.x;
  int wave = tid >> 6;
  int lane = tid & 63;
  int l15  = lane & 15;
  int lhi  = lane >> 4;
  long n0  = (long)blockIdx.x * 80;
  int hc   = wave * 16 + l15;

  bf16x8 bw[6][4];
  #pragma unroll
  for (int ks = 0; ks < 6; ++ks)
    #pragma unroll
    for (int gg = 0; gg < 4; ++gg)
      bw[ks][gg] = load_bf8(Wcat + (size_t)(gg * 128 + hc) * 192 + ks * 32 + lhi * 8);

  float kbi = bias[hc]       * NL2E;
  float kbf = bias[128 + hc] * NL2E;
  float kbg = bias[256 + hc] * NL2E2;
  float kbo = bias[384 + hc] * NL2E;
  float c[5][4];
  #pragma unroll
  for (int g = 0; g < 5; ++g)
    #pragma unroll
    for (int r = 0; r < 4; ++r) c[g][r] = 0.f;

  size_t tstr = (size_t)N * 64;
  const __hip_bfloat16* spb = seq + (n0 + l15) * 64 + lhi * 8;

  for (int t = 0; t < 7; ++t) {
    f32x4 acc[5][4];
    #pragma unroll
    for (int g = 0; g < 5; ++g)
      #pragma unroll
      for (int gg = 0; gg < 4; ++gg)
        acc[g][gg] = (f32x4){0.f, 0.f, 0.f, 0.f};

    #pragma unroll
    for (int g = 0; g < 5; ++g) {
      const __hip_bfloat16* sp = spb + (size_t)t * tstr + (size_t)g * 16 * 64;
      bf16x8 a0 = load_bf8(sp);
      bf16x8 a1 = load_bf8(sp + 32);
      #pragma unroll
      for (int gg = 0; gg < 4; ++gg)
        acc[g][gg] = __builtin_amdgcn_mfma_f32_16x16x32_bf16(a0, bw[0][gg], acc[g][gg], 0, 0, 0);
      #pragma unroll
      for (int gg = 0; gg < 4; ++gg)
        acc[g][gg] = __builtin_amdgcn_mfma_f32_16x16x32_bf16(a1, bw[1][gg], acc[g][gg], 0, 0, 0);
    }

    if (t > 0) {
      const __hip_bfloat16* hb = &h_lds[(t + 1) & 1][0][0];
      #pragma unroll
      for (int ks = 2; ks < 6; ++ks) {
        #pragma unroll
        for (int g = 0; g < 5; ++g) {
          bf16x8 a = load_bf8(hb + (g * 16 + l15) * 136 + (ks - 2) * 32 + lhi * 8);
          #pragma unroll
          for (int gg = 0; gg < 4; ++gg)
            acc[g][gg] = __builtin_amdgcn_mfma_f32_16x16x32_bf16(a, bw[ks][gg], acc[g][gg], 0, 0, 0);
        }
      }
    }

    __hip_bfloat16* hw = &h_lds[t & 1][0][0];
    #pragma unroll
    for (int g = 0; g < 5; ++g) {
      #pragma unroll
      for (int r = 0; r < 4; ++r) {
        float si  = rcp_f(1.f + exp2_f(fmaf(acc[g][0][r], NL2E,  kbi)));
        float sf  = rcp_f(1.f + exp2_f(fmaf(acc[g][1][r], NL2E,  kbf)));
        float sg2 = rcp_f(1.f + exp2_f(fmaf(acc[g][2][r], NL2E2, kbg)));
        float so  = rcp_f(1.f + exp2_f(fmaf(acc[g][3][r], NL2E,  kbo)));
        float tg  = fmaf(2.f, sg2, -1.f);
        float cn  = fmaf(sf, c[g][r], si * tg);
        c[g][r] = cn;
        float sc2 = rcp_f(1.f + exp2_f(cn * NL2E2));
        hw[(g * 16 + lhi * 4 + r) * 136 + hc] = __float2bfloat16(so * fmaf(2.f, sc2, -1.f));
      }
    }
    __syncthreads();
  }

  if (wave < 4) {
    int col1 = wave * 16 + l15;
    float b1 = fc1b[col1];
    #pragma unroll
    for (int g = 0; g < 5; ++g) {
      f32x4 acc1v = (f32x4){0.f, 0.f, 0.f, 0.f};
      #pragma unroll
      for (int ks = 0; ks < 4; ++ks) {
        int kb = ks * 32 + lhi * 8;
        bf16x8 a = load_bf8(&h_lds[0][g * 16 + l15][kb]);
        bf16x8 b = load_bf8(W1b + col1 * 128 + kb);
        acc1v = __builtin_amdgcn_mfma_f32_16x16x32_bf16(a, b, acc1v, 0, 0, 0);
      }
      #pragma unroll
      for (int r = 0; r < 4; ++r)
        s1_lds[g * 16 + lhi * 4 + r][col1] = __float2bfloat16(fmaxf(acc1v[r] + b1, 0.f));
    }
  }
  __syncthreads();

  {
    int c2 = wave * 16 + l15;
    float b2 = fc2b[c2];
    #pragma unroll
    for (int g = 0; g < 5; ++g) {
      f32x4 acc2 = (f32x4){0.f, 0.f, 0.f, 0.f};
      #pragma unroll
      for (int ks = 0; ks < 2; ++ks) {
        int kb = ks * 32 + lhi * 8;
        bf16x8 a = load_bf8(&s1_lds[g * 16 + l15][kb]);
        bf16x8 b = load_bf8(W2b + c2 * 64 + kb);
        acc2 = __builtin_amdgcn_mfma_f32_16x16x32_bf16(a, b, acc2, 0, 0, 0);
      }
      #pragma unroll
      for (int r = 0; r < 4; ++r)
        out[(n0 + g * 16 + lhi * 4 + r) * 128 + c2] = sigm_fast(acc2[r] + b2);
    }
  }
}

extern "C" void kernel_launch(void* const* d_in, const int* in_sizes, int n_in,
                              void* d_out, int out_size, void* d_ws, size_t ws_size,
                              hipStream_t stream)
{
  const float* x     = (const float*)d_in[0];
  const int*   ei    = (const int*)d_in[1];
  const float* gcnW  = (const float*)d_in[2];
  const float* gcnb  = (const float*)d_in[3];
  const float* convW = (const float*)d_in[4];
  const float* convb = (const float*)d_in[5];
  const float* Wih   = (const float*)d_in[6];
  const float* Whh   = (const float*)d_in[7];
  const float* bih   = (const float*)d_in[8];
  const float* bhh   = (const float*)d_in[9];
  const float* fc1W  = (const float*)d_in[10];
  const float* fc1b  = (const float*)d_in[11];
  const float* fc2W  = (const float*)d_in[12];
  const float* fc2b  = (const float*)d_in[13];

  const int N = in_sizes[0] / (T_STEPS * F_IN);
  const int E = in_sizes[1] / 2;

  char* ws = (char*)d_ws;
  size_t off = 0;
  auto alloc = [&](size_t bytes) {
    void* p = ws + off;
    off = (off + bytes + 255) & ~(size_t)255;
    return p;
  };
  __hip_bfloat16* hs  = (__hip_bfloat16*)alloc((size_t)(N + 1) * 256 * 2); // [N+1][256], row N zeros
  __hip_bfloat16* seq = (__hip_bfloat16*)alloc((size_t)7 * N * 64 * 2);
  int* cnt     = (int*)alloc((size_t)N * 4);
  int* row_ptr = (int*)alloc((size_t)(N + 1) * 4);
  int* cursor  = (int*)alloc((size_t)N * 4);
  float* dinv  = (float*)alloc((size_t)N * 4);
  int* adj     = (int*)alloc((size_t)(E + 16) * 4);   // +16 slack (select-tail)
  __hip_bfloat16* Wcat = (__hip_bfloat16*)alloc(512 * 192 * 2);
  float* bias = (float*)alloc(512 * 4);
  __hip_bfloat16* W1b = (__hip_bfloat16*)alloc(64 * 128 * 2);
  __hip_bfloat16* W2b = (__hip_bfloat16*)alloc(128 * 64 * 2);
  __hip_bfloat16* Wcb = (__hip_bfloat16*)alloc(64 * 64 * 2);
  __hip_bfloat16* Wgt = (__hip_bfloat16*)alloc(32 * 128 * 2);

  hipMemsetAsync(cnt, 0, (size_t)N * 4, stream);

  int pc_work = E > PREP_TOT ? E : PREP_TOT;
  k_prep_count<<<(pc_work + 255) / 256, 256, 0, stream>>>(
      ei + E, cnt, E, Wih, Whh, bih, bhh, fc1W, fc2W, convW, gcnW,
      Wcat, bias, W1b, W2b, Wcb, Wgt, (unsigned int*)(hs + (size_t)N * 256));
  k_scan<<<1, 1024, 0, stream>>>(cnt, row_ptr, cursor, dinv, N);
  k_transform_fill<<<(N * T_STEPS) / 64, 256, 0, stream>>>(x, Wgt, dinv, hs, ei, cursor, adj, E);
  k_gather_conv<<<N / 8, 256, 0, stream>>>(row_ptr, adj, dinv, hs, gcnb, Wcb, convb, seq, N);
  k_lstm_head<<<N / 80, 512, 0, stream>>>(seq, Wcat, bias, W1b, fc1b, W2b, fc2b, (float*)d_out, N);
}